// Round 2
// baseline (4437.622 us; speedup 1.0000x reference)
//
#include <hip/hip_runtime.h>
#include <hip/hip_bf16.h>

#define NN 50000
#define EE 800000
#define HH 128

// workspace layout (in floats)
#define OFF_H    0
#define OFF_A    (NN * HH)          // 6,400,000
#define OFF_B    (2 * NN * HH)      // 12,800,000
#define OFF_DINV (3 * NN * HH)      // 19,200,000
#define OFF_S    (OFF_DINV + NN)    // 19,250,000  (3 floats used)

// ---------------- degree / dinv ----------------
__global__ void k_deg(const int* __restrict__ ei, float* __restrict__ deg) {
    int e = blockIdx.x * 256 + threadIdx.x;
    if (e < EE) atomicAdd(&deg[ei[EE + e]], 1.0f);
}

__global__ void k_dinv(float* __restrict__ d) {
    int n = blockIdx.x * 256 + threadIdx.x;
    if (n < NN) d[n] = rsqrtf(d[n] + 1.0f);
}

// ---------------- GEMM: Hout = X @ W ; Agg = dinv^2*Hout + b ----------------
__global__ __launch_bounds__(256) void k_gemm(
        const float* __restrict__ X, const float* __restrict__ W,
        const float* __restrict__ bias, const float* __restrict__ dinv,
        float* __restrict__ Hout, float* __restrict__ Agg) {
    __shared__ float Xs[32 * HH];   // 16 KB
    __shared__ float Ws[32 * HH];   // 16 KB (one 32-row K-chunk of W)
    int t = threadIdx.x;
    int row0 = blockIdx.x * 32;

    // load X tile: 32x128 floats = 1024 float4, 4 per thread
    {
        float4* Xd = (float4*)Xs;
        #pragma unroll
        for (int i = 0; i < 4; ++i) {
            int fi = t + 256 * i;
            int r = fi >> 5;              // 32 float4 per row
            int c4 = (fi & 31) << 2;
            int gr = row0 + r;
            float4 v = make_float4(0.f, 0.f, 0.f, 0.f);
            if (gr < NN) v = *(const float4*)(X + gr * HH + c4);
            Xd[fi] = v;
        }
    }

    int tc = t & 31;      // cols 4*tc .. 4*tc+3
    int tr = t >> 5;      // rows 4*tr .. 4*tr+3
    float4 acc[4];
    #pragma unroll
    for (int i = 0; i < 4; ++i) acc[i] = make_float4(0.f, 0.f, 0.f, 0.f);

    for (int kb = 0; kb < 4; ++kb) {
        __syncthreads();   // X tile ready (kb=0) / previous chunk consumed
        {
            float4* Wd = (float4*)Ws;
            const float4* Wg = (const float4*)(W + kb * 32 * HH);
            #pragma unroll
            for (int i = 0; i < 4; ++i) Wd[t + 256 * i] = Wg[t + 256 * i];
        }
        __syncthreads();
        #pragma unroll
        for (int k = 0; k < 32; ++k) {
            float4 wv = *(float4*)(Ws + k * HH + (tc << 2));
            #pragma unroll
            for (int i = 0; i < 4; ++i) {
                float xv = Xs[(4 * tr + i) * HH + kb * 32 + k];
                acc[i].x += xv * wv.x;
                acc[i].y += xv * wv.y;
                acc[i].z += xv * wv.z;
                acc[i].w += xv * wv.w;
            }
        }
    }

    float4 bv = *(const float4*)(bias + (tc << 2));
    #pragma unroll
    for (int i = 0; i < 4; ++i) {
        int gr = row0 + 4 * tr + i;
        if (gr < NN) {
            *(float4*)(Hout + gr * HH + (tc << 2)) = acc[i];
            float di = dinv[gr];
            float d2 = di * di;
            float4 g;
            g.x = acc[i].x * d2 + bv.x;
            g.y = acc[i].y * d2 + bv.y;
            g.z = acc[i].z * d2 + bv.z;
            g.w = acc[i].w * d2 + bv.w;
            *(float4*)(Agg + gr * HH + (tc << 2)) = g;
        }
    }
}

// ---------------- edge scatter: Agg[dst] += dinv[s]*dinv[d]*H[src] ----------------
__global__ __launch_bounds__(256) void k_scatter(
        const float* __restrict__ Hs, const int* __restrict__ ei,
        const float* __restrict__ dinv, float* __restrict__ Agg) {
    long long idx = (long long)blockIdx.x * 256 + threadIdx.x;  // E*32 threads
    int e = (int)(idx >> 5);
    if (e >= EE) return;
    int c4 = ((int)idx & 31) << 2;
    int s = ei[e];
    int d = ei[EE + e];
    float nrm = dinv[s] * dinv[d];
    const float4 hv = *(const float4*)(Hs + s * HH + c4);
    float* ap = Agg + d * HH + c4;
    atomicAdd(ap + 0, nrm * hv.x);
    atomicAdd(ap + 1, nrm * hv.y);
    atomicAdd(ap + 2, nrm * hv.z);
    atomicAdd(ap + 3, nrm * hv.w);
}

// ---------------- in-place ReLU ----------------
__global__ void k_relu(float* __restrict__ X) {
    int i = blockIdx.x * 256 + threadIdx.x;    // over NH/4 float4s (exact)
    float4* p = (float4*)X;
    float4 v = p[i];
    v.x = fmaxf(v.x, 0.f);
    v.y = fmaxf(v.y, 0.f);
    v.z = fmaxf(v.z, 0.f);
    v.w = fmaxf(v.w, 0.f);
    p[i] = v;
}

// ---------------- fused attention pool: out += e_n * x_n ; S += e_n ----------------
// gate in (0,1) so exp needs no max-subtraction. Final scale kernel divides by S.
__global__ __launch_bounds__(256) void k_pool(
        const float* __restrict__ X, const float* __restrict__ gw,
        const float* __restrict__ gbp, float* __restrict__ outp,
        float* __restrict__ Sp) {
    __shared__ float red[HH];
    int t = threadIdx.x;
    int lane = t & 63;
    int wid = blockIdx.x * 4 + (t >> 6);
    int nw = gridDim.x * 4;
    float gb = gbp[0];
    float gw0 = gw[2 * lane], gw1 = gw[2 * lane + 1];
    float acc0 = 0.f, acc1 = 0.f, sE = 0.f;
    for (int n = wid; n < NN; n += nw) {
        float2 xv = *(const float2*)(X + n * HH + 2 * lane);
        float p = xv.x * gw0 + xv.y * gw1;
        #pragma unroll
        for (int m = 32; m >= 1; m >>= 1) p += __shfl_xor(p, m, 64);
        float g = 1.f / (1.f + expf(-(p + gb)));
        float e = expf(g);
        acc0 += e * xv.x;
        acc1 += e * xv.y;
        if (lane == 0) sE += e;
    }
    if (t < HH) red[t] = 0.f;
    __syncthreads();
    atomicAdd(&red[2 * lane], acc0);
    atomicAdd(&red[2 * lane + 1], acc1);
    __syncthreads();
    if (lane == 0) atomicAdd(Sp, sE);
    if (t < HH) atomicAdd(&outp[t], red[t]);
}

__global__ void k_scale(float* __restrict__ outp, const float* __restrict__ Sp) {
    int i = blockIdx.x * 256 + threadIdx.x;
    if (i < 3 * HH) outp[i] /= Sp[i >> 7];
}

extern "C" void kernel_launch(void* const* d_in, const int* in_sizes, int n_in,
                              void* d_out, int out_size, void* d_ws, size_t ws_size,
                              hipStream_t stream) {
    const float* x  = (const float*)d_in[0];
    const int* ei   = (const int*)d_in[1];
    const float* W1 = (const float*)d_in[2]; const float* b1 = (const float*)d_in[3];
    const float* W2 = (const float*)d_in[4]; const float* b2 = (const float*)d_in[5];
    const float* W3 = (const float*)d_in[6]; const float* b3 = (const float*)d_in[7];
    const float* gw1 = (const float*)d_in[8];  const float* gb1 = (const float*)d_in[9];
    const float* gw2 = (const float*)d_in[10]; const float* gb2 = (const float*)d_in[11];
    const float* gw3 = (const float*)d_in[12]; const float* gb3 = (const float*)d_in[13];
    float* out = (float*)d_out;
    float* ws = (float*)d_ws;
    float* Hbuf = ws + OFF_H;
    float* A    = ws + OFF_A;
    float* B    = ws + OFF_B;
    float* dinv = ws + OFF_DINV;
    float* S    = ws + OFF_S;

    hipMemsetAsync(dinv, 0, (NN + 16) * sizeof(float), stream);  // covers S too
    hipMemsetAsync(out, 0, 3 * HH * sizeof(float), stream);

    k_deg<<<(EE + 255) / 256, 256, 0, stream>>>(ei, dinv);
    k_dinv<<<(NN + 255) / 256, 256, 0, stream>>>(dinv);

    const int GEMM_GRID = (NN + 31) / 32;      // 1563
    const int SCAT_GRID = (EE * 32) / 256;     // 100000
    const int RELU_GRID = (NN * HH / 4) / 256; // 6250

    // layer 1
    k_gemm<<<GEMM_GRID, 256, 0, stream>>>(x, W1, b1, dinv, Hbuf, A);
    k_scatter<<<SCAT_GRID, 256, 0, stream>>>(Hbuf, ei, dinv, A);
    k_relu<<<RELU_GRID, 256, 0, stream>>>(A);
    k_pool<<<128, 256, 0, stream>>>(A, gw1, gb1, out, S);
    // layer 2
    k_gemm<<<GEMM_GRID, 256, 0, stream>>>(A, W2, b2, dinv, Hbuf, B);
    k_scatter<<<SCAT_GRID, 256, 0, stream>>>(Hbuf, ei, dinv, B);
    k_relu<<<RELU_GRID, 256, 0, stream>>>(B);
    k_pool<<<128, 256, 0, stream>>>(B, gw2, gb2, out + HH, S + 1);
    // layer 3
    k_gemm<<<GEMM_GRID, 256, 0, stream>>>(B, W3, b3, dinv, Hbuf, A);
    k_scatter<<<SCAT_GRID, 256, 0, stream>>>(Hbuf, ei, dinv, A);
    k_relu<<<RELU_GRID, 256, 0, stream>>>(A);
    k_pool<<<128, 256, 0, stream>>>(A, gw3, gb3, out + 2 * HH, S + 2);

    k_scale<<<2, 256, 0, stream>>>(out, S);
}

// Round 3
// 692.215 us; speedup vs baseline: 6.4108x; 6.4108x over previous
//
#include <hip/hip_runtime.h>
#include <hip/hip_bf16.h>

#define NN 50000
#define EE 800000
#define HH 128

// workspace layout (element offsets in a float/int-sized grid)
#define OFF_H      0                       // NN*HH floats
#define OFF_A      (NN * HH)               // NN*HH floats
#define OFF_DINV   (2 * NN * HH)           // NN floats
#define OFF_DEGI   (OFF_DINV + NN)         // NN ints
#define OFF_ROWPTR (OFF_DEGI + NN)         // NN+1 ints
#define OFF_CURSOR (OFF_ROWPTR + NN + 8)   // NN ints
#define OFF_CSRC   (OFF_CURSOR + NN)       // EE ints
#define OFF_CNRM   (OFF_CSRC + EE)         // EE floats
#define OFF_S      (OFF_CNRM + EE)         // 3 floats

// ---------------- degree histogram (int) ----------------
__global__ void k_degi(const int* __restrict__ ei, int* __restrict__ degi) {
    int e = blockIdx.x * 256 + threadIdx.x;
    if (e < EE) atomicAdd(&degi[ei[EE + e]], 1);
}

__global__ void k_dinv(const int* __restrict__ degi, float* __restrict__ d) {
    int n = blockIdx.x * 256 + threadIdx.x;
    if (n < NN) d[n] = rsqrtf((float)degi[n] + 1.0f);
}

// ---------------- exclusive prefix scan over degi -> rowptr (single block) ----------------
__global__ __launch_bounds__(1024) void k_scan(const int* __restrict__ degi,
                                               int* __restrict__ rowptr) {
    __shared__ int sums[1024];
    int t = threadIdx.x;
    const int CH = (NN + 1023) / 1024;   // 49
    int beg = t * CH;
    int end = beg + CH; if (end > NN) end = NN;
    int s = 0;
    for (int i = beg; i < end; ++i) s += degi[i];
    sums[t] = s;
    __syncthreads();
    for (int off = 1; off < 1024; off <<= 1) {
        int v = (t >= off) ? sums[t - off] : 0;
        __syncthreads();
        sums[t] += v;
        __syncthreads();
    }
    int run = (t == 0) ? 0 : sums[t - 1];
    for (int i = beg; i < end; ++i) {
        rowptr[i] = run;
        run += degi[i];
    }
    if (t == 1023) rowptr[NN] = sums[1023];
}

// ---------------- CSR fill: group edges by dst ----------------
__global__ void k_fill(const int* __restrict__ ei, const int* __restrict__ rowptr,
                       int* __restrict__ cursor, const float* __restrict__ dinv,
                       int* __restrict__ csrc, float* __restrict__ cnrm) {
    int e = blockIdx.x * 256 + threadIdx.x;
    if (e >= EE) return;
    int s = ei[e];
    int d = ei[EE + e];
    int pos = rowptr[d] + atomicAdd(&cursor[d], 1);
    csrc[pos] = s;
    cnrm[pos] = dinv[s] * dinv[d];
}

// ---------------- GEMM: Hout = X @ W  (32-row tile, f32) ----------------
__global__ __launch_bounds__(256) void k_gemm(
        const float* __restrict__ X, const float* __restrict__ W,
        float* __restrict__ Hout) {
    __shared__ float Xs[32 * HH];
    __shared__ float Ws[32 * HH];
    int t = threadIdx.x;
    int row0 = blockIdx.x * 32;

    {
        float4* Xd = (float4*)Xs;
        #pragma unroll
        for (int i = 0; i < 4; ++i) {
            int fi = t + 256 * i;
            int r = fi >> 5;
            int c4 = (fi & 31) << 2;
            int gr = row0 + r;
            float4 v = make_float4(0.f, 0.f, 0.f, 0.f);
            if (gr < NN) v = *(const float4*)(X + gr * HH + c4);
            Xd[fi] = v;
        }
    }

    int tc = t & 31;
    int tr = t >> 5;
    float4 acc[4];
    #pragma unroll
    for (int i = 0; i < 4; ++i) acc[i] = make_float4(0.f, 0.f, 0.f, 0.f);

    for (int kb = 0; kb < 4; ++kb) {
        __syncthreads();
        {
            float4* Wd = (float4*)Ws;
            const float4* Wg = (const float4*)(W + kb * 32 * HH);
            #pragma unroll
            for (int i = 0; i < 4; ++i) Wd[t + 256 * i] = Wg[t + 256 * i];
        }
        __syncthreads();
        #pragma unroll
        for (int k = 0; k < 32; ++k) {
            float4 wv = *(float4*)(Ws + k * HH + (tc << 2));
            #pragma unroll
            for (int i = 0; i < 4; ++i) {
                float xv = Xs[(4 * tr + i) * HH + kb * 32 + k];
                acc[i].x += xv * wv.x;
                acc[i].y += xv * wv.y;
                acc[i].z += xv * wv.z;
                acc[i].w += xv * wv.w;
            }
        }
    }

    #pragma unroll
    for (int i = 0; i < 4; ++i) {
        int gr = row0 + 4 * tr + i;
        if (gr < NN) *(float4*)(Hout + gr * HH + (tc << 2)) = acc[i];
    }
}

// ---------------- gather-aggregate: Agg[d] = relu(b + dinv[d]^2*H[d] + sum nrm*H[s]) ----------------
__global__ __launch_bounds__(256) void k_gather(
        const float* __restrict__ H, const int* __restrict__ rowptr,
        const int* __restrict__ csrc, const float* __restrict__ cnrm,
        const float* __restrict__ dinv, const float* __restrict__ bias,
        float* __restrict__ Agg) {
    int t = threadIdx.x;
    int node = blockIdx.x * 8 + (t >> 5);
    if (node >= NN) return;
    int c4 = (t & 31) << 2;
    int beg = rowptr[node], end = rowptr[node + 1];
    float di = dinv[node];
    float d2 = di * di;
    float4 hv = *(const float4*)(H + node * HH + c4);
    float4 bv = *(const float4*)(bias + c4);
    float4 acc;
    acc.x = hv.x * d2 + bv.x;
    acc.y = hv.y * d2 + bv.y;
    acc.z = hv.z * d2 + bv.z;
    acc.w = hv.w * d2 + bv.w;

    int e = beg;
    for (; e + 4 <= end; e += 4) {
        int s0 = csrc[e], s1 = csrc[e + 1], s2 = csrc[e + 2], s3 = csrc[e + 3];
        float n0 = cnrm[e], n1 = cnrm[e + 1], n2 = cnrm[e + 2], n3 = cnrm[e + 3];
        float4 v0 = *(const float4*)(H + s0 * HH + c4);
        float4 v1 = *(const float4*)(H + s1 * HH + c4);
        float4 v2 = *(const float4*)(H + s2 * HH + c4);
        float4 v3 = *(const float4*)(H + s3 * HH + c4);
        acc.x += n0 * v0.x + n1 * v1.x + n2 * v2.x + n3 * v3.x;
        acc.y += n0 * v0.y + n1 * v1.y + n2 * v2.y + n3 * v3.y;
        acc.z += n0 * v0.z + n1 * v1.z + n2 * v2.z + n3 * v3.z;
        acc.w += n0 * v0.w + n1 * v1.w + n2 * v2.w + n3 * v3.w;
    }
    for (; e < end; ++e) {
        int s = csrc[e];
        float nrm = cnrm[e];
        float4 v = *(const float4*)(H + s * HH + c4);
        acc.x += nrm * v.x;
        acc.y += nrm * v.y;
        acc.z += nrm * v.z;
        acc.w += nrm * v.w;
    }
    acc.x = fmaxf(acc.x, 0.f);
    acc.y = fmaxf(acc.y, 0.f);
    acc.z = fmaxf(acc.z, 0.f);
    acc.w = fmaxf(acc.w, 0.f);
    *(float4*)(Agg + node * HH + c4) = acc;
}

// ---------------- fused attention pool ----------------
__global__ __launch_bounds__(256) void k_pool(
        const float* __restrict__ X, const float* __restrict__ gw,
        const float* __restrict__ gbp, float* __restrict__ outp,
        float* __restrict__ Sp) {
    __shared__ float red[HH];
    int t = threadIdx.x;
    int lane = t & 63;
    int wid = blockIdx.x * 4 + (t >> 6);
    int nw = gridDim.x * 4;
    float gb = gbp[0];
    float gw0 = gw[2 * lane], gw1 = gw[2 * lane + 1];
    float acc0 = 0.f, acc1 = 0.f, sE = 0.f;
    for (int n = wid; n < NN; n += nw) {
        float2 xv = *(const float2*)(X + n * HH + 2 * lane);
        float p = xv.x * gw0 + xv.y * gw1;
        #pragma unroll
        for (int m = 32; m >= 1; m >>= 1) p += __shfl_xor(p, m, 64);
        float g = 1.f / (1.f + expf(-(p + gb)));
        float e = expf(g);
        acc0 += e * xv.x;
        acc1 += e * xv.y;
        if (lane == 0) sE += e;
    }
    if (t < HH) red[t] = 0.f;
    __syncthreads();
    atomicAdd(&red[2 * lane], acc0);
    atomicAdd(&red[2 * lane + 1], acc1);
    __syncthreads();
    if (lane == 0) atomicAdd(Sp, sE);
    if (t < HH) atomicAdd(&outp[t], red[t]);
}

__global__ void k_scale(float* __restrict__ outp, const float* __restrict__ Sp) {
    int i = blockIdx.x * 256 + threadIdx.x;
    if (i < 3 * HH) outp[i] /= Sp[i >> 7];
}

extern "C" void kernel_launch(void* const* d_in, const int* in_sizes, int n_in,
                              void* d_out, int out_size, void* d_ws, size_t ws_size,
                              hipStream_t stream) {
    const float* x  = (const float*)d_in[0];
    const int* ei   = (const int*)d_in[1];
    const float* W1 = (const float*)d_in[2]; const float* b1 = (const float*)d_in[3];
    const float* W2 = (const float*)d_in[4]; const float* b2 = (const float*)d_in[5];
    const float* W3 = (const float*)d_in[6]; const float* b3 = (const float*)d_in[7];
    const float* gw1 = (const float*)d_in[8];  const float* gb1 = (const float*)d_in[9];
    const float* gw2 = (const float*)d_in[10]; const float* gb2 = (const float*)d_in[11];
    const float* gw3 = (const float*)d_in[12]; const float* gb3 = (const float*)d_in[13];
    float* out = (float*)d_out;
    float* ws  = (float*)d_ws;

    float* Hbuf   = ws + OFF_H;
    float* A      = ws + OFF_A;
    float* dinv   = ws + OFF_DINV;
    int*   degi   = (int*)(ws + OFF_DEGI);
    int*   rowptr = (int*)(ws + OFF_ROWPTR);
    int*   cursor = (int*)(ws + OFF_CURSOR);
    int*   csrc   = (int*)(ws + OFF_CSRC);
    float* cnrm   = ws + OFF_CNRM;
    float* S      = ws + OFF_S;

    hipMemsetAsync(degi, 0, NN * sizeof(int), stream);
    hipMemsetAsync(cursor, 0, NN * sizeof(int), stream);
    hipMemsetAsync(S, 0, 16, stream);
    hipMemsetAsync(out, 0, 3 * HH * sizeof(float), stream);

    const int EG = (EE + 255) / 256;
    const int NG = (NN + 255) / 256;
    k_degi<<<EG, 256, 0, stream>>>(ei, degi);
    k_dinv<<<NG, 256, 0, stream>>>(degi, dinv);
    k_scan<<<1, 1024, 0, stream>>>(degi, rowptr);
    k_fill<<<EG, 256, 0, stream>>>(ei, rowptr, cursor, dinv, csrc, cnrm);

    const int GEMM_GRID = (NN + 31) / 32;   // 1563
    const int GATH_GRID = (NN + 7) / 8;     // 6250

    // layer 1
    k_gemm<<<GEMM_GRID, 256, 0, stream>>>(x, W1, Hbuf);
    k_gather<<<GATH_GRID, 256, 0, stream>>>(Hbuf, rowptr, csrc, cnrm, dinv, b1, A);
    k_pool<<<128, 256, 0, stream>>>(A, gw1, gb1, out, S);
    // layer 2
    k_gemm<<<GEMM_GRID, 256, 0, stream>>>(A, W2, Hbuf);
    k_gather<<<GATH_GRID, 256, 0, stream>>>(Hbuf, rowptr, csrc, cnrm, dinv, b2, A);
    k_pool<<<128, 256, 0, stream>>>(A, gw2, gb2, out + HH, S + 1);
    // layer 3
    k_gemm<<<GEMM_GRID, 256, 0, stream>>>(A, W3, Hbuf);
    k_gather<<<GATH_GRID, 256, 0, stream>>>(Hbuf, rowptr, csrc, cnrm, dinv, b3, A);
    k_pool<<<128, 256, 0, stream>>>(A, gw3, gb3, out + 2 * HH, S + 2);

    k_scale<<<2, 256, 0, stream>>>(out, S);
}

// Round 4
// 594.412 us; speedup vs baseline: 7.4656x; 1.1645x over previous
//
#include <hip/hip_runtime.h>
#include <hip/hip_bf16.h>

#define NN 50000
#define EE 800000
#define HH 128

typedef __attribute__((ext_vector_type(8))) short bf16x8;
typedef __attribute__((ext_vector_type(4))) float f32x4;

// workspace layout (float-element offsets)
#define OFF_H      0                        // NN*HH f32
#define OFF_A      (NN * HH)                // NN*HH f32
#define OFF_ABF    (2 * NN * HH)            // NN*HH bf16 (NN*HH/2 floats)
#define OFF_DINV   (OFF_ABF + NN * HH / 2)  // NN f32
#define OFF_DEGI   (OFF_DINV + NN)          // NN int
#define OFF_ROWPTR (OFF_DEGI + NN)          // NN+8 int
#define OFF_CURSOR (OFF_ROWPTR + NN + 8)    // NN int
#define OFF_CSRC   (OFF_CURSOR + NN)        // EE int
#define OFF_CNRM   (OFF_CSRC + EE)          // EE f32
#define OFF_PART   (OFF_CNRM + EE)          // 128 int (partials + offs)
#define OFF_S      (OFF_PART + 128)         // 4 f32
#define OFF_WHP    (OFF_S + 4)              // 3*16384 bf16 = 24576 floats
#define OFF_WLP    (OFF_WHP + 24576)        // 3*16384 bf16

__device__ inline unsigned short f2bf(float f) {
    unsigned u = __float_as_uint(f);
    u += 0x7fffu + ((u >> 16) & 1u);
    return (unsigned short)(u >> 16);
}
__device__ inline float bf2f(unsigned short h) {
    unsigned u = ((unsigned)h) << 16;
    return __uint_as_float(u);
}

// ---------------- degree histogram ----------------
__global__ void k_degi(const int* __restrict__ ei, int* __restrict__ degi) {
    int e = blockIdx.x * 256 + threadIdx.x;
    if (e < EE) atomicAdd(&degi[ei[EE + e]], 1);
}

__global__ void k_dinv(const int* __restrict__ degi, float* __restrict__ d) {
    int n = blockIdx.x * 256 + threadIdx.x;
    if (n < NN) d[n] = rsqrtf((float)degi[n] + 1.0f);
}

// ---------------- 3-stage exclusive scan (degi -> rowptr) ----------------
__global__ __launch_bounds__(1024) void k_scanA(const int* __restrict__ degi,
                                                int* __restrict__ partial) {
    __shared__ int r[1024];
    int t = threadIdx.x;
    int i = blockIdx.x * 1024 + t;
    r[t] = (i < NN) ? degi[i] : 0;
    __syncthreads();
    for (int off = 512; off >= 1; off >>= 1) {
        if (t < off) r[t] += r[t + off];
        __syncthreads();
    }
    if (t == 0) partial[blockIdx.x] = r[0];
}

__global__ void k_scanB(const int* __restrict__ partial, int* __restrict__ offs,
                        int* __restrict__ rowptr) {
    int t = threadIdx.x;   // 64 threads
    int v = (t < 49) ? partial[t] : 0;
    #pragma unroll
    for (int off = 1; off <= 32; off <<= 1) {
        int u = __shfl_up(v, off, 64);
        if (t >= off) v += u;
    }
    int excl = __shfl_up(v, 1, 64);
    if (t == 0) excl = 0;
    if (t < 49) offs[t] = excl;
    if (t == 0) rowptr[NN] = EE;
}

__global__ __launch_bounds__(1024) void k_scanC(const int* __restrict__ degi,
                                                const int* __restrict__ offs,
                                                int* __restrict__ rowptr) {
    __shared__ int s[1024];
    int t = threadIdx.x;
    int i = blockIdx.x * 1024 + t;
    int v = (i < NN) ? degi[i] : 0;
    s[t] = v;
    __syncthreads();
    for (int off = 1; off < 1024; off <<= 1) {
        int u = (t >= off) ? s[t - off] : 0;
        __syncthreads();
        s[t] += u;
        __syncthreads();
    }
    if (i < NN) rowptr[i] = offs[blockIdx.x] + s[t] - v;
}

// ---------------- CSR fill ----------------
__global__ void k_fill(const int* __restrict__ ei, const int* __restrict__ rowptr,
                       int* __restrict__ cursor, const float* __restrict__ dinv,
                       int* __restrict__ csrc, float* __restrict__ cnrm) {
    int e = blockIdx.x * 256 + threadIdx.x;
    if (e >= EE) return;
    int s = ei[e];
    int d = ei[EE + e];
    int pos = rowptr[d] + atomicAdd(&cursor[d], 1);
    csrc[pos] = s;
    cnrm[pos] = dinv[s] * dinv[d];
}

// ---------------- pack W1..W3 into MFMA B-fragment order, split hi/lo ----------------
// frag index r = (ct*4+ks)*64+lane ; elem j: B[k][n], k=ks*32+(lane>>4)*8+j, n=ct*16+(lane&15)
__global__ void k_wprep(const float* __restrict__ Wa, const float* __restrict__ Wb,
                        const float* __restrict__ Wc,
                        short* __restrict__ Whp, short* __restrict__ Wlp) {
    int g = blockIdx.x * 256 + threadIdx.x;   // [0, 3*2048)
    if (g >= 3 * 2048) return;
    int layer = g >> 11;
    int r = g & 2047;
    int ct = r >> 8, ks = (r >> 6) & 3, lane = r & 63;
    const float* W = (layer == 0) ? Wa : (layer == 1) ? Wb : Wc;
    int kbase = ks * 32 + ((lane >> 4) << 3);
    int n = ct * 16 + (lane & 15);
    #pragma unroll
    for (int j = 0; j < 8; ++j) {
        float w = W[(kbase + j) * HH + n];
        unsigned short hi = f2bf(w);
        unsigned short lo = f2bf(w - bf2f(hi));
        Whp[(size_t)layer * 16384 + r * 8 + j] = (short)hi;
        Wlp[(size_t)layer * 16384 + r * 8 + j] = (short)lo;
    }
}

// ---------------- f32 -> bf16 convert (layer-1 input) ----------------
__global__ void k_cvt(const float* __restrict__ X, short* __restrict__ Xbf) {
    int i = blockIdx.x * 256 + threadIdx.x;   // over NN*HH/4
    float4 v = ((const float4*)X)[i];
    ushort4 o;
    o.x = f2bf(v.x); o.y = f2bf(v.y); o.z = f2bf(v.z); o.w = f2bf(v.w);
    ((ushort4*)Xbf)[i] = o;
}

// ---------------- MFMA GEMM: H = Xbf @ (Wh + Wl) ----------------
__global__ __launch_bounds__(256) void k_gemm(
        const short* __restrict__ Xbf, const short* __restrict__ Whp,
        const short* __restrict__ Wlp, float* __restrict__ Hout) {
    int t = threadIdx.x;
    int lane = t & 63;
    int wv = t >> 6;
    int row0 = blockIdx.x * 64 + wv * 16;
    int arow = row0 + (lane & 15);
    int koff = (lane >> 4) << 3;

    bf16x8 a[4];
    #pragma unroll
    for (int ks = 0; ks < 4; ++ks) {
        if (arow < NN)
            a[ks] = *(const bf16x8*)(Xbf + (size_t)arow * HH + ks * 32 + koff);
        else
            a[ks] = (bf16x8)(short)0;
    }

    const bf16x8* Bh = (const bf16x8*)Whp;
    const bf16x8* Bl = (const bf16x8*)Wlp;
    int crow0 = row0 + ((lane >> 4) << 2);
    int ccol = lane & 15;

    #pragma unroll
    for (int ct = 0; ct < 8; ++ct) {
        f32x4 acc = {0.f, 0.f, 0.f, 0.f};
        #pragma unroll
        for (int ks = 0; ks < 4; ++ks)
            acc = __builtin_amdgcn_mfma_f32_16x16x32_bf16(a[ks], Bh[(ct * 4 + ks) * 64 + lane], acc, 0, 0, 0);
        #pragma unroll
        for (int ks = 0; ks < 4; ++ks)
            acc = __builtin_amdgcn_mfma_f32_16x16x32_bf16(a[ks], Bl[(ct * 4 + ks) * 64 + lane], acc, 0, 0, 0);
        #pragma unroll
        for (int r = 0; r < 4; ++r) {
            int cr = crow0 + r;
            if (cr < NN) Hout[(size_t)cr * HH + ct * 16 + ccol] = acc[r];
        }
    }
}

// ---------------- gather-aggregate: A = relu(b + d2*H + sum nrm*H[s]); also bf16 copy ----------------
__global__ __launch_bounds__(256) void k_gather(
        const float* __restrict__ H, const int* __restrict__ rowptr,
        const int* __restrict__ csrc, const float* __restrict__ cnrm,
        const float* __restrict__ dinv, const float* __restrict__ bias,
        float* __restrict__ Agg, short* __restrict__ Abf) {
    int t = threadIdx.x;
    int node = blockIdx.x * 8 + (t >> 5);
    if (node >= NN) return;
    int c4 = (t & 31) << 2;
    int beg = rowptr[node], end = rowptr[node + 1];
    float di = dinv[node];
    float d2 = di * di;
    float4 hv = *(const float4*)(H + (size_t)node * HH + c4);
    float4 bv = *(const float4*)(bias + c4);
    float4 acc;
    acc.x = hv.x * d2 + bv.x;
    acc.y = hv.y * d2 + bv.y;
    acc.z = hv.z * d2 + bv.z;
    acc.w = hv.w * d2 + bv.w;

    int e = beg;
    for (; e + 4 <= end; e += 4) {
        int s0 = csrc[e], s1 = csrc[e + 1], s2 = csrc[e + 2], s3 = csrc[e + 3];
        float n0 = cnrm[e], n1 = cnrm[e + 1], n2 = cnrm[e + 2], n3 = cnrm[e + 3];
        float4 v0 = *(const float4*)(H + (size_t)s0 * HH + c4);
        float4 v1 = *(const float4*)(H + (size_t)s1 * HH + c4);
        float4 v2 = *(const float4*)(H + (size_t)s2 * HH + c4);
        float4 v3 = *(const float4*)(H + (size_t)s3 * HH + c4);
        acc.x += n0 * v0.x + n1 * v1.x + n2 * v2.x + n3 * v3.x;
        acc.y += n0 * v0.y + n1 * v1.y + n2 * v2.y + n3 * v3.y;
        acc.z += n0 * v0.z + n1 * v1.z + n2 * v2.z + n3 * v3.z;
        acc.w += n0 * v0.w + n1 * v1.w + n2 * v2.w + n3 * v3.w;
    }
    for (; e < end; ++e) {
        int s = csrc[e];
        float nrm = cnrm[e];
        float4 v = *(const float4*)(H + (size_t)s * HH + c4);
        acc.x += nrm * v.x;
        acc.y += nrm * v.y;
        acc.z += nrm * v.z;
        acc.w += nrm * v.w;
    }
    acc.x = fmaxf(acc.x, 0.f);
    acc.y = fmaxf(acc.y, 0.f);
    acc.z = fmaxf(acc.z, 0.f);
    acc.w = fmaxf(acc.w, 0.f);
    *(float4*)(Agg + (size_t)node * HH + c4) = acc;
    ushort4 o;
    o.x = f2bf(acc.x); o.y = f2bf(acc.y); o.z = f2bf(acc.z); o.w = f2bf(acc.w);
    *(ushort4*)(Abf + (size_t)node * HH + c4) = o;
}

// ---------------- fused attention pool ----------------
__global__ __launch_bounds__(256) void k_pool(
        const float* __restrict__ X, const float* __restrict__ gw,
        const float* __restrict__ gbp, float* __restrict__ outp,
        float* __restrict__ Sp) {
    __shared__ float red[HH];
    int t = threadIdx.x;
    int lane = t & 63;
    int wid = blockIdx.x * 4 + (t >> 6);
    int nw = gridDim.x * 4;
    float gb = gbp[0];
    float gw0 = gw[2 * lane], gw1 = gw[2 * lane + 1];
    float acc0 = 0.f, acc1 = 0.f, sE = 0.f;
    for (int n = wid; n < NN; n += nw) {
        float2 xv = *(const float2*)(X + (size_t)n * HH + 2 * lane);
        float p = xv.x * gw0 + xv.y * gw1;
        #pragma unroll
        for (int m = 32; m >= 1; m >>= 1) p += __shfl_xor(p, m, 64);
        float g = 1.f / (1.f + expf(-(p + gb)));
        float e = expf(g);
        acc0 += e * xv.x;
        acc1 += e * xv.y;
        if (lane == 0) sE += e;
    }
    if (t < HH) red[t] = 0.f;
    __syncthreads();
    atomicAdd(&red[2 * lane], acc0);
    atomicAdd(&red[2 * lane + 1], acc1);
    __syncthreads();
    if (lane == 0) atomicAdd(Sp, sE);
    if (t < HH) atomicAdd(&outp[t], red[t]);
}

__global__ void k_scale(float* __restrict__ outp, const float* __restrict__ Sp) {
    int i = blockIdx.x * 256 + threadIdx.x;
    if (i < 3 * HH) outp[i] /= Sp[i >> 7];
}

extern "C" void kernel_launch(void* const* d_in, const int* in_sizes, int n_in,
                              void* d_out, int out_size, void* d_ws, size_t ws_size,
                              hipStream_t stream) {
    const float* x  = (const float*)d_in[0];
    const int* ei   = (const int*)d_in[1];
    const float* W1 = (const float*)d_in[2]; const float* b1 = (const float*)d_in[3];
    const float* W2 = (const float*)d_in[4]; const float* b2 = (const float*)d_in[5];
    const float* W3 = (const float*)d_in[6]; const float* b3 = (const float*)d_in[7];
    const float* gw1 = (const float*)d_in[8];  const float* gb1 = (const float*)d_in[9];
    const float* gw2 = (const float*)d_in[10]; const float* gb2 = (const float*)d_in[11];
    const float* gw3 = (const float*)d_in[12]; const float* gb3 = (const float*)d_in[13];
    float* out = (float*)d_out;
    float* ws  = (float*)d_ws;

    float* Hbuf   = ws + OFF_H;
    float* A      = ws + OFF_A;
    short* Abf    = (short*)(ws + OFF_ABF);
    float* dinv   = ws + OFF_DINV;
    int*   degi   = (int*)(ws + OFF_DEGI);
    int*   rowptr = (int*)(ws + OFF_ROWPTR);
    int*   cursor = (int*)(ws + OFF_CURSOR);
    int*   csrc   = (int*)(ws + OFF_CSRC);
    float* cnrm   = ws + OFF_CNRM;
    int*   part   = (int*)(ws + OFF_PART);
    int*   offs   = part + 64;
    float* S      = ws + OFF_S;
    short* Whp    = (short*)(ws + OFF_WHP);
    short* Wlp    = (short*)(ws + OFF_WLP);

    hipMemsetAsync(degi, 0, NN * sizeof(int), stream);
    hipMemsetAsync(cursor, 0, NN * sizeof(int), stream);
    hipMemsetAsync(S, 0, 16, stream);
    hipMemsetAsync(out, 0, 3 * HH * sizeof(float), stream);

    const int EG = (EE + 255) / 256;
    const int NG = (NN + 255) / 256;
    k_degi<<<EG, 256, 0, stream>>>(ei, degi);
    k_dinv<<<NG, 256, 0, stream>>>(degi, dinv);
    k_scanA<<<49, 1024, 0, stream>>>(degi, part);
    k_scanB<<<1, 64, 0, stream>>>(part, offs, rowptr);
    k_scanC<<<49, 1024, 0, stream>>>(degi, offs, rowptr);
    k_fill<<<EG, 256, 0, stream>>>(ei, rowptr, cursor, dinv, csrc, cnrm);
    k_wprep<<<24, 256, 0, stream>>>(W1, W2, W3, Whp, Wlp);
    k_cvt<<<(NN * HH / 4 + 255) / 256, 256, 0, stream>>>(x, Abf);

    const int GEMM_GRID = (NN + 63) / 64;   // 782
    const int GATH_GRID = (NN + 7) / 8;     // 6250

    // layer 1
    k_gemm<<<GEMM_GRID, 256, 0, stream>>>(Abf, Whp, Wlp, Hbuf);
    k_gather<<<GATH_GRID, 256, 0, stream>>>(Hbuf, rowptr, csrc, cnrm, dinv, b1, A, Abf);
    k_pool<<<128, 256, 0, stream>>>(A, gw1, gb1, out, S);
    // layer 2
    k_gemm<<<GEMM_GRID, 256, 0, stream>>>(Abf, Whp + 16384, Wlp + 16384, Hbuf);
    k_gather<<<GATH_GRID, 256, 0, stream>>>(Hbuf, rowptr, csrc, cnrm, dinv, b2, A, Abf);
    k_pool<<<128, 256, 0, stream>>>(A, gw2, gb2, out + HH, S + 1);
    // layer 3
    k_gemm<<<GEMM_GRID, 256, 0, stream>>>(Abf, Whp + 32768, Wlp + 32768, Hbuf);
    k_gather<<<GATH_GRID, 256, 0, stream>>>(Hbuf, rowptr, csrc, cnrm, dinv, b3, A, Abf);
    k_pool<<<128, 256, 0, stream>>>(A, gw3, gb3, out + 2 * HH, S + 2);

    k_scale<<<2, 256, 0, stream>>>(out, S);
}

// Round 5
// 467.011 us; speedup vs baseline: 9.5022x; 1.2728x over previous
//
#include <hip/hip_runtime.h>
#include <hip/hip_bf16.h>

#define NN 50000
#define EE 800000
#define HH 128

typedef __attribute__((ext_vector_type(8))) short bf16x8;
typedef __attribute__((ext_vector_type(4))) float f32x4;

// workspace layout (float-element offsets)
#define OFF_HBF    0                        // NN*HH bf16 = NN*HH/2 floats
#define OFF_ABF    (NN * HH / 2)            // NN*HH bf16
#define OFF_DINV   (NN * HH)                // NN f32
#define OFF_DEGI   (OFF_DINV + NN)          // NN int
#define OFF_ROWPTR (OFF_DEGI + NN)          // NN+8 int
#define OFF_CURSOR (OFF_ROWPTR + NN + 8)    // NN int
#define OFF_CSRC   (OFF_CURSOR + NN)        // EE int
#define OFF_CNRM   (OFF_CSRC + EE)          // EE f32
#define OFF_PART   (OFF_CNRM + EE)          // 128 int
#define OFF_S      (OFF_PART + 128)         // 4 f32
#define OFF_WHP    (OFF_S + 4)              // 3*16384 bf16
#define OFF_WLP    (OFF_WHP + 24576)        // 3*16384 bf16

__device__ inline unsigned short f2bf(float f) {
    unsigned u = __float_as_uint(f);
    u += 0x7fffu + ((u >> 16) & 1u);
    return (unsigned short)(u >> 16);
}
__device__ inline float bf2f(unsigned short h) {
    unsigned u = ((unsigned)h) << 16;
    return __uint_as_float(u);
}

// ---------------- degree histogram ----------------
__global__ void k_degi(const int* __restrict__ ei, int* __restrict__ degi) {
    int e = blockIdx.x * 256 + threadIdx.x;
    if (e < EE) atomicAdd(&degi[ei[EE + e]], 1);
}

__global__ void k_dinv(const int* __restrict__ degi, float* __restrict__ d) {
    int n = blockIdx.x * 256 + threadIdx.x;
    if (n < NN) d[n] = rsqrtf((float)degi[n] + 1.0f);
}

// ---------------- 3-stage exclusive scan (degi -> rowptr) ----------------
__global__ __launch_bounds__(1024) void k_scanA(const int* __restrict__ degi,
                                                int* __restrict__ partial) {
    __shared__ int r[1024];
    int t = threadIdx.x;
    int i = blockIdx.x * 1024 + t;
    r[t] = (i < NN) ? degi[i] : 0;
    __syncthreads();
    for (int off = 512; off >= 1; off >>= 1) {
        if (t < off) r[t] += r[t + off];
        __syncthreads();
    }
    if (t == 0) partial[blockIdx.x] = r[0];
}

__global__ void k_scanB(const int* __restrict__ partial, int* __restrict__ offs,
                        int* __restrict__ rowptr) {
    int t = threadIdx.x;   // 64 threads
    int v = (t < 49) ? partial[t] : 0;
    #pragma unroll
    for (int off = 1; off <= 32; off <<= 1) {
        int u = __shfl_up(v, off, 64);
        if (t >= off) v += u;
    }
    int excl = __shfl_up(v, 1, 64);
    if (t == 0) excl = 0;
    if (t < 49) offs[t] = excl;
    if (t == 0) rowptr[NN] = EE;
}

__global__ __launch_bounds__(1024) void k_scanC(const int* __restrict__ degi,
                                                const int* __restrict__ offs,
                                                int* __restrict__ rowptr) {
    __shared__ int s[1024];
    int t = threadIdx.x;
    int i = blockIdx.x * 1024 + t;
    int v = (i < NN) ? degi[i] : 0;
    s[t] = v;
    __syncthreads();
    for (int off = 1; off < 1024; off <<= 1) {
        int u = (t >= off) ? s[t - off] : 0;
        __syncthreads();
        s[t] += u;
        __syncthreads();
    }
    if (i < NN) rowptr[i] = offs[blockIdx.x] + s[t] - v;
}

// ---------------- CSR fill ----------------
__global__ void k_fill(const int* __restrict__ ei, const int* __restrict__ rowptr,
                       int* __restrict__ cursor, const float* __restrict__ dinv,
                       int* __restrict__ csrc, float* __restrict__ cnrm) {
    int e = blockIdx.x * 256 + threadIdx.x;
    if (e >= EE) return;
    int s = ei[e];
    int d = ei[EE + e];
    int pos = rowptr[d] + atomicAdd(&cursor[d], 1);
    csrc[pos] = s;
    cnrm[pos] = dinv[s] * dinv[d];
}

// ---------------- pack W into MFMA B-fragment order, split hi/lo ----------------
__global__ void k_wprep(const float* __restrict__ Wa, const float* __restrict__ Wb,
                        const float* __restrict__ Wc,
                        short* __restrict__ Whp, short* __restrict__ Wlp) {
    int g = blockIdx.x * 256 + threadIdx.x;   // [0, 3*2048)
    if (g >= 3 * 2048) return;
    int layer = g >> 11;
    int r = g & 2047;
    int ct = r >> 8, ks = (r >> 6) & 3, lane = r & 63;
    const float* W = (layer == 0) ? Wa : (layer == 1) ? Wb : Wc;
    int kbase = ks * 32 + ((lane >> 4) << 3);
    int n = ct * 16 + (lane & 15);
    #pragma unroll
    for (int j = 0; j < 8; ++j) {
        float w = W[(kbase + j) * HH + n];
        unsigned short hi = f2bf(w);
        unsigned short lo = f2bf(w - bf2f(hi));
        Whp[(size_t)layer * 16384 + r * 8 + j] = (short)hi;
        Wlp[(size_t)layer * 16384 + r * 8 + j] = (short)lo;
    }
}

// ---------------- f32 -> bf16 convert (layer-1 input) ----------------
__global__ void k_cvt(const float* __restrict__ X, short* __restrict__ Xbf) {
    int i = blockIdx.x * 256 + threadIdx.x;   // over NN*HH/4
    float4 v = ((const float4*)X)[i];
    ushort4 o;
    o.x = f2bf(v.x); o.y = f2bf(v.y); o.z = f2bf(v.z); o.w = f2bf(v.w);
    ((ushort4*)Xbf)[i] = o;
}

// ---------------- MFMA GEMM: Hbf = bf16(Xbf @ (Wh + Wl)) ----------------
__global__ __launch_bounds__(256) void k_gemm(
        const short* __restrict__ Xbf, const short* __restrict__ Whp,
        const short* __restrict__ Wlp, short* __restrict__ Hout) {
    int t = threadIdx.x;
    int lane = t & 63;
    int wv = t >> 6;
    int row0 = blockIdx.x * 64 + wv * 16;
    int arow = row0 + (lane & 15);
    int koff = (lane >> 4) << 3;

    bf16x8 a[4];
    #pragma unroll
    for (int ks = 0; ks < 4; ++ks) {
        if (arow < NN)
            a[ks] = *(const bf16x8*)(Xbf + (size_t)arow * HH + ks * 32 + koff);
        else
            a[ks] = (bf16x8)(short)0;
    }

    const bf16x8* Bh = (const bf16x8*)Whp;
    const bf16x8* Bl = (const bf16x8*)Wlp;
    int crow0 = row0 + ((lane >> 4) << 2);
    int ccol = lane & 15;

    #pragma unroll
    for (int ct = 0; ct < 8; ++ct) {
        f32x4 acc = {0.f, 0.f, 0.f, 0.f};
        #pragma unroll
        for (int ks = 0; ks < 4; ++ks)
            acc = __builtin_amdgcn_mfma_f32_16x16x32_bf16(a[ks], Bh[(ct * 4 + ks) * 64 + lane], acc, 0, 0, 0);
        #pragma unroll
        for (int ks = 0; ks < 4; ++ks)
            acc = __builtin_amdgcn_mfma_f32_16x16x32_bf16(a[ks], Bl[(ct * 4 + ks) * 64 + lane], acc, 0, 0, 0);
        #pragma unroll
        for (int r = 0; r < 4; ++r) {
            int cr = crow0 + r;
            if (cr < NN)
                Hout[(size_t)cr * HH + ct * 16 + ccol] = (short)f2bf(acc[r]);
        }
    }
}

// ---------------- gather-aggregate (bf16 rows): Abf = bf16(relu(b + d2*H + sum nrm*H[s])) ----------------
__global__ __launch_bounds__(256) void k_gather(
        const short* __restrict__ H, const int* __restrict__ rowptr,
        const int* __restrict__ csrc, const float* __restrict__ cnrm,
        const float* __restrict__ dinv, const float* __restrict__ bias,
        short* __restrict__ Abf) {
    int t = threadIdx.x;
    int node = blockIdx.x * 8 + (t >> 5);
    if (node >= NN) return;
    int c4 = (t & 31) << 2;
    int beg = rowptr[node], end = rowptr[node + 1];
    float di = dinv[node];
    float d2 = di * di;
    ushort4 hv = *(const ushort4*)(H + (size_t)node * HH + c4);
    float4 bv = *(const float4*)(bias + c4);
    float4 acc;
    acc.x = bf2f(hv.x) * d2 + bv.x;
    acc.y = bf2f(hv.y) * d2 + bv.y;
    acc.z = bf2f(hv.z) * d2 + bv.z;
    acc.w = bf2f(hv.w) * d2 + bv.w;

    int e = beg;
    for (; e + 4 <= end; e += 4) {
        int s0 = csrc[e], s1 = csrc[e + 1], s2 = csrc[e + 2], s3 = csrc[e + 3];
        float n0 = cnrm[e], n1 = cnrm[e + 1], n2 = cnrm[e + 2], n3 = cnrm[e + 3];
        ushort4 v0 = *(const ushort4*)(H + (size_t)s0 * HH + c4);
        ushort4 v1 = *(const ushort4*)(H + (size_t)s1 * HH + c4);
        ushort4 v2 = *(const ushort4*)(H + (size_t)s2 * HH + c4);
        ushort4 v3 = *(const ushort4*)(H + (size_t)s3 * HH + c4);
        acc.x += n0 * bf2f(v0.x) + n1 * bf2f(v1.x) + n2 * bf2f(v2.x) + n3 * bf2f(v3.x);
        acc.y += n0 * bf2f(v0.y) + n1 * bf2f(v1.y) + n2 * bf2f(v2.y) + n3 * bf2f(v3.y);
        acc.z += n0 * bf2f(v0.z) + n1 * bf2f(v1.z) + n2 * bf2f(v2.z) + n3 * bf2f(v3.z);
        acc.w += n0 * bf2f(v0.w) + n1 * bf2f(v1.w) + n2 * bf2f(v2.w) + n3 * bf2f(v3.w);
    }
    for (; e < end; ++e) {
        int s = csrc[e];
        float nrm = cnrm[e];
        ushort4 v = *(const ushort4*)(H + (size_t)s * HH + c4);
        acc.x += nrm * bf2f(v.x);
        acc.y += nrm * bf2f(v.y);
        acc.z += nrm * bf2f(v.z);
        acc.w += nrm * bf2f(v.w);
    }
    ushort4 o;
    o.x = f2bf(fmaxf(acc.x, 0.f));
    o.y = f2bf(fmaxf(acc.y, 0.f));
    o.z = f2bf(fmaxf(acc.z, 0.f));
    o.w = f2bf(fmaxf(acc.w, 0.f));
    *(ushort4*)(Abf + (size_t)node * HH + c4) = o;
}

// ---------------- fused attention pool (bf16 input) ----------------
__global__ __launch_bounds__(256) void k_pool(
        const short* __restrict__ X, const float* __restrict__ gw,
        const float* __restrict__ gbp, float* __restrict__ outp,
        float* __restrict__ Sp) {
    __shared__ float red[HH];
    int t = threadIdx.x;
    int lane = t & 63;
    int wid = blockIdx.x * 4 + (t >> 6);
    int nw = gridDim.x * 4;
    float gb = gbp[0];
    float gw0 = gw[2 * lane], gw1 = gw[2 * lane + 1];
    float acc0 = 0.f, acc1 = 0.f, sE = 0.f;
    for (int n = wid; n < NN; n += nw) {
        ushort2 xv = *(const ushort2*)(X + (size_t)n * HH + 2 * lane);
        float x0 = bf2f(xv.x), x1 = bf2f(xv.y);
        float p = x0 * gw0 + x1 * gw1;
        #pragma unroll
        for (int m = 32; m >= 1; m >>= 1) p += __shfl_xor(p, m, 64);
        float g = 1.f / (1.f + expf(-(p + gb)));
        float e = expf(g);
        acc0 += e * x0;
        acc1 += e * x1;
        if (lane == 0) sE += e;
    }
    if (t < HH) red[t] = 0.f;
    __syncthreads();
    atomicAdd(&red[2 * lane], acc0);
    atomicAdd(&red[2 * lane + 1], acc1);
    __syncthreads();
    if (lane == 0) atomicAdd(Sp, sE);
    if (t < HH) atomicAdd(&outp[t], red[t]);
}

__global__ void k_scale(float* __restrict__ outp, const float* __restrict__ Sp) {
    int i = blockIdx.x * 256 + threadIdx.x;
    if (i < 3 * HH) outp[i] /= Sp[i >> 7];
}

extern "C" void kernel_launch(void* const* d_in, const int* in_sizes, int n_in,
                              void* d_out, int out_size, void* d_ws, size_t ws_size,
                              hipStream_t stream) {
    const float* x  = (const float*)d_in[0];
    const int* ei   = (const int*)d_in[1];
    const float* W1 = (const float*)d_in[2]; const float* b1 = (const float*)d_in[3];
    const float* W2 = (const float*)d_in[4]; const float* b2 = (const float*)d_in[5];
    const float* W3 = (const float*)d_in[6]; const float* b3 = (const float*)d_in[7];
    const float* gw1 = (const float*)d_in[8];  const float* gb1 = (const float*)d_in[9];
    const float* gw2 = (const float*)d_in[10]; const float* gb2 = (const float*)d_in[11];
    const float* gw3 = (const float*)d_in[12]; const float* gb3 = (const float*)d_in[13];
    float* out = (float*)d_out;
    float* ws  = (float*)d_ws;

    short* Hbf    = (short*)(ws + OFF_HBF);
    short* Abf    = (short*)(ws + OFF_ABF);
    float* dinv   = ws + OFF_DINV;
    int*   degi   = (int*)(ws + OFF_DEGI);
    int*   rowptr = (int*)(ws + OFF_ROWPTR);
    int*   cursor = (int*)(ws + OFF_CURSOR);
    int*   csrc   = (int*)(ws + OFF_CSRC);
    float* cnrm   = ws + OFF_CNRM;
    int*   part   = (int*)(ws + OFF_PART);
    int*   offs   = part + 64;
    float* S      = ws + OFF_S;
    short* Whp    = (short*)(ws + OFF_WHP);
    short* Wlp    = (short*)(ws + OFF_WLP);

    hipMemsetAsync(degi, 0, NN * sizeof(int), stream);
    hipMemsetAsync(cursor, 0, NN * sizeof(int), stream);
    hipMemsetAsync(S, 0, 16, stream);
    hipMemsetAsync(out, 0, 3 * HH * sizeof(float), stream);

    const int EG = (EE + 255) / 256;
    const int NG = (NN + 255) / 256;
    k_degi<<<EG, 256, 0, stream>>>(ei, degi);
    k_dinv<<<NG, 256, 0, stream>>>(degi, dinv);
    k_scanA<<<49, 1024, 0, stream>>>(degi, part);
    k_scanB<<<1, 64, 0, stream>>>(part, offs, rowptr);
    k_scanC<<<49, 1024, 0, stream>>>(degi, offs, rowptr);
    k_fill<<<EG, 256, 0, stream>>>(ei, rowptr, cursor, dinv, csrc, cnrm);
    k_wprep<<<24, 256, 0, stream>>>(W1, W2, W3, Whp, Wlp);
    k_cvt<<<(NN * HH / 4 + 255) / 256, 256, 0, stream>>>(x, Abf);

    const int GEMM_GRID = (NN + 63) / 64;   // 782
    const int GATH_GRID = (NN + 7) / 8;     // 6250

    // layer 1
    k_gemm<<<GEMM_GRID, 256, 0, stream>>>(Abf, Whp, Wlp, Hbf);
    k_gather<<<GATH_GRID, 256, 0, stream>>>(Hbf, rowptr, csrc, cnrm, dinv, b1, Abf);
    k_pool<<<512, 256, 0, stream>>>(Abf, gw1, gb1, out, S);
    // layer 2
    k_gemm<<<GEMM_GRID, 256, 0, stream>>>(Abf, Whp + 16384, Wlp + 16384, Hbf);
    k_gather<<<GATH_GRID, 256, 0, stream>>>(Hbf, rowptr, csrc, cnrm, dinv, b2, Abf);
    k_pool<<<512, 256, 0, stream>>>(Abf, gw2, gb2, out + HH, S + 1);
    // layer 3
    k_gemm<<<GEMM_GRID, 256, 0, stream>>>(Abf, Whp + 32768, Wlp + 32768, Hbf);
    k_gather<<<GATH_GRID, 256, 0, stream>>>(Hbf, rowptr, csrc, cnrm, dinv, b3, Abf);
    k_pool<<<512, 256, 0, stream>>>(Abf, gw3, gb3, out + 2 * HH, S + 2);

    k_scale<<<2, 256, 0, stream>>>(out, S);
}